// Round 5
// baseline (488.704 us; speedup 1.0000x reference)
//
#include <hip/hip_runtime.h>
#include <math.h>

// Problem constants
#define B_ 32
#define C_ 512
#define G_ 32
#define N_ 1024          // H*W
#define OC3_ 1536        // 3*C
#define EPS_ 1e-5f

typedef __attribute__((ext_vector_type(8))) short short8;
typedef __attribute__((ext_vector_type(4))) float f32x4;

// fp32 -> bf16 RNE
__device__ inline unsigned short f2bf(float f) {
    unsigned u = __builtin_bit_cast(unsigned, f);
    u += 0x7fffu + ((u >> 16) & 1u);
    return (unsigned short)(u >> 16);
}
__device__ inline unsigned pack2(float lo, float hi) {
    return (unsigned)f2bf(lo) | ((unsigned)f2bf(hi) << 16);
}
__device__ inline float bf2f(unsigned short u) {
    return __builtin_bit_cast(float, ((unsigned)u) << 16);
}

// async global->LDS 16 B per lane (gfx950). LDS dest = wave-uniform base +
// lane*16; all call sites use base + tid*8 (shorts).
typedef const __attribute__((address_space(1))) unsigned int* gas_u32;
typedef __attribute__((address_space(3))) unsigned int* las_u32;
__device__ __forceinline__ void cp16(unsigned short* lds, const unsigned short* g) {
    __builtin_amdgcn_global_load_lds((gas_u32)g, (las_u32)lds, 16, 0, 0);
}

// Shared batch->XCD decomposition: 1-D grids decoded so bid%8 == bz%8 when
// nb%8==0 -- with the round-robin linear-id->XCD mapping, batch bz's blocks
// (and its few-MB inter-kernel buffers) stay on one XCD's 4 MB L2 across the
// whole chain hhatT -> GEMM1 -> GEMM2 -> softmax -> GEMM3 -> GEMM4.
__device__ __forceinline__ void xcd_decode(int bid, int nbpb, int nbz,
                                           int& bz, int& local) {
    if ((nbz & 7) == 0) {
        int xcd = bid & 7;
        int rest = bid >> 3;
        local = rest % nbpb;
        bz = (rest / nbpb) * 8 + xcd;
    } else {
        bz = bid / nbpb;
        local = bid % nbpb;
    }
}

// ---------------------------------------------------------------------------
// R14: merged prep. Blocks 0..1023: GroupNorm stats, one block per (b,g).
// Blocks 1024..2047: fp32->bf16 weight convert (wqkv then wproj).
// Saves two dispatch tails vs gn_stats + 2x cvt.
// ---------------------------------------------------------------------------
__global__ __launch_bounds__(256) void prep_kernel(
    const float* __restrict__ x, float* __restrict__ stats,
    const float* __restrict__ qkv_w, unsigned short* __restrict__ wqkv,
    const float* __restrict__ proj_w, unsigned short* __restrict__ wproj)
{
    __shared__ float r1[256], r2[256];
    int bid = blockIdx.x;
    if (bid < 1024) {
        int bg = bid;
        const float4* xv = (const float4*)(x + (size_t)bg * 16 * N_);
        float s = 0.f, ss = 0.f;
        for (int i = threadIdx.x; i < 4096; i += 256) {
            float4 v = xv[i];
            s  += v.x + v.y + v.z + v.w;
            ss += v.x*v.x + v.y*v.y + v.z*v.z + v.w*v.w;
        }
        r1[threadIdx.x] = s; r2[threadIdx.x] = ss;
        __syncthreads();
        for (int off = 128; off > 0; off >>= 1) {
            if (threadIdx.x < off) {
                r1[threadIdx.x] += r1[threadIdx.x + off];
                r2[threadIdx.x] += r2[threadIdx.x + off];
            }
            __syncthreads();
        }
        if (threadIdx.x == 0) {
            float mean = r1[0] * (1.f / 16384.f);
            float var  = r2[0] * (1.f / 16384.f) - mean * mean;
            stats[bg * 2 + 0] = mean;
            stats[bg * 2 + 1] = rsqrtf(var + EPS_);
        }
    } else {
        int i = (bid - 1024) * 256 + threadIdx.x;   // float4 index
        const int nQ = OC3_ * C_ / 4;               // 196608
        float4 v;
        uint2 o;
        if (i < nQ) {
            v = ((const float4*)qkv_w)[i];
            o.x = pack2(v.x, v.y); o.y = pack2(v.z, v.w);
            ((uint2*)wqkv)[i] = o;
        } else {
            int j = i - nQ;                          // < 65536
            v = ((const float4*)proj_w)[j];
            o.x = pack2(v.x, v.y); o.y = pack2(v.z, v.w);
            ((uint2*)wproj)[j] = o;
        }
    }
}

// ---------------------------------------------------------------------------
// hhatT producer: x[b][c][n] fp32 (coalesced reads) -> GN affine ->
// hhatT[bz][n][c] bf16 via 64x64 LDS tile transpose. 1-D grid, XCD-pinned.
// ---------------------------------------------------------------------------
__global__ __launch_bounds__(256) void hhatT_kernel(
    const float* __restrict__ x, const float* __restrict__ stats,
    const float* __restrict__ nw, const float* __restrict__ nbias,
    unsigned short* __restrict__ hhatT, long sH, int b0, int nbz)
{
    int bz, local;
    xcd_decode(blockIdx.x, 128, nbz, bz, local);
    int b = b0 + bz;
    int nt = (local & 15) * 64, ct = (local >> 4) * 64;
    const float* xb = x + (size_t)b * C_ * N_;
    const float* st = stats + b * 2 * G_;

    __shared__ float T[64][65];
    int tid = threadIdx.x;

    #pragma unroll
    for (int p = 0; p < 4; ++p) {
        int c = p * 16 + (tid >> 4);
        int n4 = (tid & 15) * 4;
        float4 v = *(const float4*)&xb[(size_t)(ct + c) * N_ + nt + n4];
        int g = (ct + c) >> 4;
        float w0 = nw[ct + c] * st[g * 2 + 1];
        float bb = nbias[ct + c] - st[g * 2] * w0;
        T[c][n4]   = v.x * w0 + bb;
        T[c][n4+1] = v.y * w0 + bb;
        T[c][n4+2] = v.z * w0 + bb;
        T[c][n4+3] = v.w * w0 + bb;
    }
    __syncthreads();
    #pragma unroll
    for (int p = 0; p < 2; ++p) {
        int n  = p * 32 + (tid >> 3);
        int c8 = (tid & 7) * 8;
        short8 s;
        #pragma unroll
        for (int u = 0; u < 8; ++u) s[u] = (short)f2bf(T[c8 + u][n]);
        *(short8*)&hhatT[(size_t)bz * sH + (size_t)(nt + n) * C_ + ct + c8] = s;
    }
}

// ---------------------------------------------------------------------------
// R14: 128x256 GEMM: D[row][col] = sum_k A[row][k]*B[col][k]  (+ epilogue)
// BK=32, 4 waves (2x2 over 128rows x 256cols; per-wave 64x128, acc 4x8).
//
// WHY 256-wide (R14): R9-R13 counters show every GEMM latency-bound at
// ~575 TF with ALL pipes <30% (MfmaUtil 24, VALU 29, HBM 21, Occ 27) -- at
// K=512 only 16 iterations amortize prologue+epilogue, and the per-iteration
// barrier drain dominates. Doubling MFMA-per-barrier (16->32/wave) halves
// the drain count per output element. LDS 48 KB (A dbuf 16K + B dbuf 32K),
// est ~200 VGPR -> 2 blocks/CU nominal, at-or-above the measured average.
//
// K-loop staging/swizzle identical involution as verified (conflicts=0):
// physical chunk p at row R holds global chunk p ^ ((R>>1)&3); frag read
// fco = (q ^ ((lm>>1)&3))*8.
//
// EPILOGUE (R12 structure, R14-corrected swizzle key): acc -> 32 KB LDS ->
// full-wave short8/float4 bursts. bf16 key = q<<1 (bank-group word-bits 3,4
// = key bits 1,2 = q -> the 4 q-groups hit 4 distinct 8-word blocks ->
// conflict-free; R13's (4i+q)&7 put q in bits 0,1 -> pairs collided 4-way,
// SQ_LDS_BANK_CONFLICT went UP to 1.57M). Reader key w<<1 (rr>>2 = 4k+w),
// wave-uniform. fp32 path key (lr>>2)&7 re-derived: worst 2-way (free), kept.
//
// EPI: 2 bf16 *scale | 3 bf16 | 4 fp32 +bias[row]+aux (residual)
//      5 fused qkv: local 0..31 -> qkT[n][o]=hhatT.Wqk+b (bx=li&7,by=li>>3)
//                   local 32..47 -> v[c][n]=Wv.hhatT+b   (bx=li&3,by=li>>2)
// ---------------------------------------------------------------------------
template<int EPI>
__global__ __launch_bounds__(256) void gemmk(
    const unsigned short* __restrict__ A, long sA, int lda,
    const unsigned short* __restrict__ B, long sB, int ldb,
    void* __restrict__ Dv, long sD, int ldd,
    const float* __restrict__ bias,
    const float* __restrict__ aux, long sAux,
    int K, float scale, int gx, int gy, int nbz)
{
    int bz, local;
    xcd_decode(blockIdx.x, gx * gy, nbz, bz, local);

    int bx, by;
    bool p2 = false;
    if constexpr (EPI == 5) {
        p2 = local >= 32;
        int li = p2 ? local - 32 : local;
        bx = p2 ? (li & 3) : (li & 7);
        by = p2 ? (li >> 2) : (li >> 3);
    } else {
        bx = local % gx;
        by = local / gx;
    }

    const unsigned short *Ab, *Bb;
    if constexpr (EPI == 5) {
        // lda == ldb == C_ at the EPI5 call site.
        if (p2) {
            Ab = B + (size_t)(1024 + bx * 128) * ldb;
            Bb = A + (size_t)bz * sA + (size_t)by * 256 * lda;
        } else {
            Ab = A + (size_t)bz * sA + (size_t)bx * 128 * lda;
            Bb = B + (size_t)by * 256 * ldb;
        }
    } else {
        Ab = A + (size_t)bz * sA + (size_t)bx * 128 * lda;
        Bb = B + (size_t)bz * sB + (size_t)by * 256 * ldb;
    }

    // 48 KB: As dbuf 2x4096 shorts, Bs dbuf 2x8192 shorts.
    // Epilogue reuses the first 32 KB as the output staging tile.
    __shared__ __align__(16) unsigned short smem[24576];
    #define AS_(c) (smem + (c) * 4096)
    #define BS_(c) (smem + 8192 + (c) * 8192)

    int tid = threadIdx.x;
    int w = tid >> 6, lane = tid & 63;
    int lm = lane & 15, q = lane >> 4;
    int wrow = (w >> 1) * 64, wcol = (w & 1) * 128;

    f32x4 acc[4][8];
    #pragma unroll
    for (int i = 0; i < 4; ++i)
        #pragma unroll
        for (int j = 0; j < 8; ++j) acc[i][j] = (f32x4)(0.f);

    int srow = tid >> 2;                              // staging row (0..63)
    int skc  = (((tid & 3) ^ ((tid >> 3) & 3))) * 8;  // swizzled global chunk
    int fco  = (q ^ ((lm >> 1) & 3)) * 8;             // frag physical chunk

    const unsigned short* a0p = Ab + (size_t)srow        * lda + skc;
    const unsigned short* a1p = Ab + (size_t)(64 + srow) * lda + skc;
    const unsigned short* bp[4];
    #pragma unroll
    for (int s = 0; s < 4; ++s)
        bp[s] = Bb + (size_t)(s * 64 + srow) * ldb + skc;

    // prologue: stage tile 0 into buffer 0 (6 cp16/thread)
    cp16(AS_(0) + tid * 8,        a0p);
    cp16(AS_(0) + 2048 + tid * 8, a1p);
    #pragma unroll
    for (int s = 0; s < 4; ++s)
        cp16(BS_(0) + s * 2048 + tid * 8, bp[s]);

    int nIter = K >> 5;
    for (int it = 0; it < nIter; ++it) {
        int cur = it & 1;
        __syncthreads();   // drains tile-it DMA (in flight since iter it-1)
        if (it + 1 < nIter) {
            int off = (it + 1) * 32;
            int nxt = cur ^ 1;
            cp16(AS_(nxt) + tid * 8,        a0p + off);
            cp16(AS_(nxt) + 2048 + tid * 8, a1p + off);
            #pragma unroll
            for (int s = 0; s < 4; ++s)
                cp16(BS_(nxt) + s * 2048 + tid * 8, bp[s] + off);
        }
        short8 af[4], bf[8];
        #pragma unroll
        for (int i = 0; i < 4; ++i)
            af[i] = *(const short8*)&AS_(cur)[(wrow + i * 16 + lm) * 32 + fco];
        #pragma unroll
        for (int j = 0; j < 8; ++j)
            bf[j] = *(const short8*)&BS_(cur)[(wcol + j * 16 + lm) * 32 + fco];
        #pragma unroll
        for (int i = 0; i < 4; ++i)
            #pragma unroll
            for (int j = 0; j < 8; ++j)
                acc[i][j] = __builtin_amdgcn_mfma_f32_16x16x32_bf16(
                    af[i], bf[j], acc[i][j], 0, 0, 0);
    }

    // ----------------------- coalesced epilogue ----------------------------
    __syncthreads();   // all waves done with staging LDS; safe to reuse

    if constexpr (EPI != 4) {
        // bf16: two 128x128 half-tiles through 32 KB. Wave w owns cols
        // (w&1)*128..+127 -> stages in pass h == (w&1); all threads copy out.
        unsigned short* Ts = smem;
        #pragma unroll
        for (int h = 0; h < 2; ++h) {
            if (h) __syncthreads();             // pass-0 copy-out done
            if ((w & 1) == h) {
                #pragma unroll
                for (int j = 0; j < 8; ++j) {
                    int lc = j * 16 + lm;       // 0..127 within half
                    float cb = 0.f;
                    if constexpr (EPI == 5) {
                        if (!p2) cb = bias[by * 256 + h * 128 + lc];
                    }
                    #pragma unroll
                    for (int i = 0; i < 4; ++i) {
                        #pragma unroll
                        for (int r = 0; r < 4; ++r) {
                            int lr = wrow + i * 16 + q * 4 + r;
                            float vle = acc[i][j][r];
                            if constexpr (EPI == 2) vle *= scale;
                            else if constexpr (EPI == 5)
                                vle += p2 ? bias[1024 + bx * 128 + lr] : cb;
                            Ts[lr * 128 + (lc ^ (q << 4))] = f2bf(vle);
                        }
                    }
                }
            }
            __syncthreads();
            size_t doff = 0;
            if constexpr (EPI == 5) { if (p2) doff = (size_t)(1u << 20); }
            unsigned short* Dp = (unsigned short*)Dv + doff +
                (size_t)bz * sD + (size_t)(bx * 128) * ldd + by * 256 + h * 128;
            #pragma unroll
            for (int k = 0; k < 8; ++k) {
                int flat = k * 2048 + tid * 8;      // shorts, 8-aligned
                int rr = flat >> 7, cc = flat & 127;
                // writer key q<<1 at word-bits 3,4 -> shorts XOR (q<<4);
                // reader q(rr) = (rr>>2)&3 = (4k+w)&3 = w  (wave-uniform)
                short8 vv = *(const short8*)&Ts[flat ^ (w << 4)];
                *(short8*)&Dp[(size_t)rr * ldd + cc] = vv;
            }
        }
    } else {
        // fp32 + residual: four 128x64 quarter-tiles through 32 KB.
        // Quarter qd cols qd*64; wave w participates when (w&1)==(qd>>1),
        // using its j range (qd&1)*4..+3.
        float* Ts32 = (float*)smem;                 // 8192 floats
        float* Dp = (float*)Dv + (size_t)bz * sD + (size_t)(bx * 128) * ldd + by * 256;
        const float* Ap = aux + (size_t)bz * sAux + (size_t)(bx * 128) * ldd + by * 256;
        #pragma unroll
        for (int qd = 0; qd < 4; ++qd) {
            if (qd) __syncthreads();                // prev copy-out done
            if ((w & 1) == (qd >> 1)) {
                #pragma unroll
                for (int jj = 0; jj < 4; ++jj) {
                    int j = (qd & 1) * 4 + jj;
                    int lch = jj * 16 + lm;         // 0..63 within quarter
                    #pragma unroll
                    for (int i = 0; i < 4; ++i) {
                        #pragma unroll
                        for (int r = 0; r < 4; ++r) {
                            int lr = wrow + i * 16 + q * 4 + r;
                            int wkey = (lr >> 2) & 7;   // worst 2-way = free
                            Ts32[lr * 64 + (lch ^ (wkey << 3))] =
                                acc[i][j][r] + bias[bx * 128 + lr];
                        }
                    }
                }
            }
            __syncthreads();
            #pragma unroll
            for (int k = 0; k < 8; ++k) {
                int flat = k * 1024 + tid * 4;      // floats, 4-aligned
                int rr = flat >> 6, cc = flat & 63;
                int key = (4 * k + w) & 7;          // = (rr>>2)&7, wave-uniform
                f32x4 vv = *(const f32x4*)&Ts32[flat ^ (key << 3)];
                size_t go = (size_t)rr * ldd + qd * 64 + cc;
                f32x4 av = *(const f32x4*)&Ap[go];
                *(f32x4*)&Dp[go] = vv + av;
            }
        }
    }
    #undef AS_
    #undef BS_
}

// ---------------------------------------------------------------------------
// Softmax: in-place on bf16 scores. One WAVE per row (16 elems/lane),
// shuffle reductions, no barriers. Block = 4 waves = 4 rows.
// 1-D grid, XCD-pinned: keeps sc on the same XCD L2 as GEMM2/GEMM3.
// ---------------------------------------------------------------------------
__global__ __launch_bounds__(256) void softmax_kernel(
    unsigned short* __restrict__ sc, long sSc, int nbz)
{
    int bz, local;
    xcd_decode(blockIdx.x, 256, nbz, bz, local);
    int row = local * 4 + (threadIdx.x >> 6);
    int lane = threadIdx.x & 63;
    unsigned short* p = sc + (size_t)bz * sSc + (size_t)row * N_ + lane * 16;

    short8 s0 = *(const short8*)p;
    short8 s1 = *(const short8*)(p + 8);
    float v[16];
    #pragma unroll
    for (int i = 0; i < 8; ++i) {
        v[i]     = bf2f((unsigned short)s0[i]);
        v[8 + i] = bf2f((unsigned short)s1[i]);
    }
    float m = v[0];
    #pragma unroll
    for (int i = 1; i < 16; ++i) m = fmaxf(m, v[i]);
    #pragma unroll
    for (int off = 32; off > 0; off >>= 1) m = fmaxf(m, __shfl_xor(m, off, 64));

    float sum = 0.f;
    #pragma unroll
    for (int i = 0; i < 16; ++i) { v[i] = __expf(v[i] - m); sum += v[i]; }
    #pragma unroll
    for (int off = 32; off > 0; off >>= 1) sum += __shfl_xor(sum, off, 64);
    float inv = 1.f / sum;

    short8 o0, o1;
    #pragma unroll
    for (int i = 0; i < 8; ++i) {
        o0[i] = (short)f2bf(v[i] * inv);
        o1[i] = (short)f2bf(v[8 + i] * inv);
    }
    *(short8*)p = o0;
    *(short8*)(p + 8) = o1;
}

// ---------------------------------------------------------------------------
extern "C" void kernel_launch(void* const* d_in, const int* in_sizes, int n_in,
                              void* d_out, int out_size, void* d_ws, size_t ws_size,
                              hipStream_t stream) {
    const float* x      = (const float*)d_in[0];
    const float* norm_w = (const float*)d_in[1];
    const float* norm_b = (const float*)d_in[2];
    const float* qkv_w  = (const float*)d_in[3];
    const float* qkv_b  = (const float*)d_in[4];
    const float* proj_w = (const float*)d_in[5];
    const float* proj_b = (const float*)d_in[6];
    float* out = (float*)d_out;

    // Fixed region: stats (8 KB) + bf16 weights (2 MB).
    char* ws = (char*)d_ws;
    float* stats = (float*)ws;
    unsigned short* wqkv  = (unsigned short*)(ws + 8192);   // 1536x512
    unsigned short* wproj = wqkv + (size_t)OC3_ * C_;       // 512x512
    char* base = (char*)(wproj + (size_t)C_ * C_);
    const size_t fixed = 8192 + (size_t)OC3_ * C_ * 2 + (size_t)C_ * C_ * 2;

    // Per-batch aliased region: 6 MB.
    //   [0,2M)  qkT bf16 [n][1024]
    //   [2,3M)  v bf16 [c][n]     (= qkT + (1<<20) shorts; EPI5 part 2)
    //   [3,4M)  hhatT bf16 [n][c] -> after GEMM2 reused as houtT bf16 [n][c]
    //   [4,6M)  sc bf16 [n][m]    -> softmax in-place -> attn
    const size_t REG = 6u << 20;
    const long RSH = (long)(REG / 2);         // region stride in shorts

    size_t avail = ws_size > fixed ? ws_size - fixed : 0;
    int chunk = (int)(avail / REG);
    if (chunk < 1) chunk = 1;
    if (chunk > B_) chunk = B_;

    prep_kernel<<<dim3(2048), dim3(256), 0, stream>>>(
        x, stats, qkv_w, wqkv, proj_w, wproj);

    const float scale = 0.044194173824159216f;  // 512^-0.5

    unsigned short* qkT   = (unsigned short*)base;
    unsigned short* vbuf  = (unsigned short*)(base + (2u << 20));
    unsigned short* hhatT = (unsigned short*)(base + (3u << 20));
    unsigned short* houtT = (unsigned short*)(base + (3u << 20)); // aliases hhatT
    unsigned short* sc    = (unsigned short*)(base + (4u << 20)); // scores/attn

    for (int b0 = 0; b0 < B_; b0 += chunk) {
        int nb = B_ - b0 < chunk ? B_ - b0 : chunk;

        hhatT_kernel<<<dim3(128 * nb), dim3(256), 0, stream>>>(
            x, stats, norm_w, norm_b, hhatT, RSH, b0, nb);

        // GEMM1 fused (EPI5): qkT[n][0:1024] (+bias[col]) AND v[c][n]
        // (+bias[1024+row]); 48 blocks/batch (32 qk + 16 v).
        gemmk<5><<<dim3(48 * nb), dim3(256), 0, stream>>>(
            hhatT, RSH, C_,  wqkv, 0, C_,
            qkT, RSH, 1024,  qkv_b, nullptr, 0, C_, 0.f, 48, 1, nb);

        // GEMM2: sc[n][m] = bf16( scale * qkT[n][0:512] . qkT[m][512:1024] )
        gemmk<2><<<dim3(8 * 4 * nb), dim3(256), 0, stream>>>(
            qkT, RSH, 1024,  qkT + 512, RSH, 1024,
            sc, RSH, N_,  nullptr, nullptr, 0, C_, scale, 8, 4, nb);

        softmax_kernel<<<dim3(256 * nb), dim3(256), 0, stream>>>(sc, RSH, nb);

        // GEMM3: houtT[n][c] = attn[n][:] . v[c][:]   (K = 1024)
        gemmk<3><<<dim3(8 * 2 * nb), dim3(256), 0, stream>>>(
            sc, RSH, N_,  vbuf, RSH, N_,
            houtT, RSH, C_,  nullptr, nullptr, 0, N_, 0.f, 8, 2, nb);

        // GEMM4: out[o][n] = pw[o][:] . houtT[n][:] + pb[o] + x[o][n]
        gemmk<4><<<dim3(4 * 4 * nb), dim3(256), 0, stream>>>(
            wproj, 0, C_,  houtT, RSH, C_,
            out + (size_t)b0 * C_ * N_, (long)C_ * N_, N_,
            proj_b, x + (size_t)b0 * C_ * N_, (long)C_ * N_, C_, 0.f, 4, 4, nb);
    }
}

// Round 6
// 373.351 us; speedup vs baseline: 1.3090x; 1.3090x over previous
//
#include <hip/hip_runtime.h>
#include <math.h>

// Problem constants
#define B_ 32
#define C_ 512
#define G_ 32
#define N_ 1024          // H*W
#define OC3_ 1536        // 3*C
#define EPS_ 1e-5f

typedef __attribute__((ext_vector_type(8))) short short8;
typedef __attribute__((ext_vector_type(4))) float f32x4;

// fp32 -> bf16 RNE
__device__ inline unsigned short f2bf(float f) {
    unsigned u = __builtin_bit_cast(unsigned, f);
    u += 0x7fffu + ((u >> 16) & 1u);
    return (unsigned short)(u >> 16);
}
__device__ inline unsigned pack2(float lo, float hi) {
    return (unsigned)f2bf(lo) | ((unsigned)f2bf(hi) << 16);
}
__device__ inline float bf2f(unsigned short u) {
    return __builtin_bit_cast(float, ((unsigned)u) << 16);
}

// async global->LDS 16 B per lane (gfx950). LDS dest = wave-uniform base +
// lane*16; all call sites use base + tid*8 (shorts).
typedef const __attribute__((address_space(1))) unsigned int* gas_u32;
typedef __attribute__((address_space(3))) unsigned int* las_u32;
__device__ __forceinline__ void cp16(unsigned short* lds, const unsigned short* g) {
    __builtin_amdgcn_global_load_lds((gas_u32)g, (las_u32)lds, 16, 0, 0);
}

// Shared batch->XCD decomposition: 1-D grids decoded so bid%8 == bz%8 when
// nb%8==0 -- with the round-robin linear-id->XCD mapping, batch bz's blocks
// (and its few-MB inter-kernel buffers) stay on one XCD's 4 MB L2 across the
// whole chain hhatT -> GEMM1 -> GEMM2 -> softmax -> GEMM3 -> GEMM4.
__device__ __forceinline__ void xcd_decode(int bid, int nbpb, int nbz,
                                           int& bz, int& local) {
    if ((nbz & 7) == 0) {
        int xcd = bid & 7;
        int rest = bid >> 3;
        local = rest % nbpb;
        bz = (rest / nbpb) * 8 + xcd;
    } else {
        bz = bid / nbpb;
        local = bid % nbpb;
    }
}

// ---------------------------------------------------------------------------
// Merged prep. Blocks 0..1023: GroupNorm stats, one block per (b,g).
// Blocks 1024..2047: fp32->bf16 weight convert (wqkv then wproj).
// ---------------------------------------------------------------------------
__global__ __launch_bounds__(256) void prep_kernel(
    const float* __restrict__ x, float* __restrict__ stats,
    const float* __restrict__ qkv_w, unsigned short* __restrict__ wqkv,
    const float* __restrict__ proj_w, unsigned short* __restrict__ wproj)
{
    __shared__ float r1[256], r2[256];
    int bid = blockIdx.x;
    if (bid < 1024) {
        int bg = bid;
        const float4* xv = (const float4*)(x + (size_t)bg * 16 * N_);
        float s = 0.f, ss = 0.f;
        for (int i = threadIdx.x; i < 4096; i += 256) {
            float4 v = xv[i];
            s  += v.x + v.y + v.z + v.w;
            ss += v.x*v.x + v.y*v.y + v.z*v.z + v.w*v.w;
        }
        r1[threadIdx.x] = s; r2[threadIdx.x] = ss;
        __syncthreads();
        for (int off = 128; off > 0; off >>= 1) {
            if (threadIdx.x < off) {
                r1[threadIdx.x] += r1[threadIdx.x + off];
                r2[threadIdx.x] += r2[threadIdx.x + off];
            }
            __syncthreads();
        }
        if (threadIdx.x == 0) {
            float mean = r1[0] * (1.f / 16384.f);
            float var  = r2[0] * (1.f / 16384.f) - mean * mean;
            stats[bg * 2 + 0] = mean;
            stats[bg * 2 + 1] = rsqrtf(var + EPS_);
        }
    } else {
        int i = (bid - 1024) * 256 + threadIdx.x;   // float4 index
        const int nQ = OC3_ * C_ / 4;               // 196608
        float4 v;
        uint2 o;
        if (i < nQ) {
            v = ((const float4*)qkv_w)[i];
            o.x = pack2(v.x, v.y); o.y = pack2(v.z, v.w);
            ((uint2*)wqkv)[i] = o;
        } else {
            int j = i - nQ;                          // < 65536
            v = ((const float4*)proj_w)[j];
            o.x = pack2(v.x, v.y); o.y = pack2(v.z, v.w);
            ((uint2*)wproj)[j] = o;
        }
    }
}

// ---------------------------------------------------------------------------
// hhatT producer: x[b][c][n] fp32 (coalesced reads) -> GN affine ->
// hhatT[bz][n][c] bf16 via 64x64 LDS tile transpose. 1-D grid, XCD-pinned.
// ---------------------------------------------------------------------------
__global__ __launch_bounds__(256) void hhatT_kernel(
    const float* __restrict__ x, const float* __restrict__ stats,
    const float* __restrict__ nw, const float* __restrict__ nbias,
    unsigned short* __restrict__ hhatT, long sH, int b0, int nbz)
{
    int bz, local;
    xcd_decode(blockIdx.x, 128, nbz, bz, local);
    int b = b0 + bz;
    int nt = (local & 15) * 64, ct = (local >> 4) * 64;
    const float* xb = x + (size_t)b * C_ * N_;
    const float* st = stats + b * 2 * G_;

    __shared__ float T[64][65];
    int tid = threadIdx.x;

    #pragma unroll
    for (int p = 0; p < 4; ++p) {
        int c = p * 16 + (tid >> 4);
        int n4 = (tid & 15) * 4;
        float4 v = *(const float4*)&xb[(size_t)(ct + c) * N_ + nt + n4];
        int g = (ct + c) >> 4;
        float w0 = nw[ct + c] * st[g * 2 + 1];
        float bb = nbias[ct + c] - st[g * 2] * w0;
        T[c][n4]   = v.x * w0 + bb;
        T[c][n4+1] = v.y * w0 + bb;
        T[c][n4+2] = v.z * w0 + bb;
        T[c][n4+3] = v.w * w0 + bb;
    }
    __syncthreads();
    #pragma unroll
    for (int p = 0; p < 2; ++p) {
        int n  = p * 32 + (tid >> 3);
        int c8 = (tid & 7) * 8;
        short8 s;
        #pragma unroll
        for (int u = 0; u < 8; ++u) s[u] = (short)f2bf(T[c8 + u][n]);
        *(short8*)&hhatT[(size_t)bz * sH + (size_t)(nt + n) * C_ + ct + c8] = s;
    }
}

// ---------------------------------------------------------------------------
// 128x128 GEMM: D[row][col] = sum_k A[row][k] * B[col][k]  (+ epilogue)
// 4 waves (2x2 of 64x64), acc 4x4 (R14's 4x8 collapsed occupancy to
// 1 block/CU -> 2x regression; reverted per pre-commit).
//
// R15: BK=64 SUB-TILED STAGING. The per-iteration __syncthreads() drain
// (vmcnt(0)+lgkmcnt(0)) is the serial term (m233); halve its count by
// staging TWO 32-K sub-tiles per double-buffer entry (8 cp16/iter) and
// running two MFMA sub-passes per barrier (16 -> 32 MFMA/wave/barrier).
// LDS 32->64 KB: occupancy stays 2 blocks/CU (VGPR 144 already binds at 2;
// 160/64 = 2), so barrier-halving is occupancy-free -- unlike m132/R14.
// All intra-sub-tile addressing identical to the verified kernel
// (staging involution chunk^=(row>>1)&3, frag fco=(q^((lm>>1)&3))*8;
// K-loop conflicts measured 0).
//
// EPILOGUE: acc -> LDS -> full-wave short8/float4 bursts (R12), with the
// R14-PROVEN bf16 key q<<4 shorts (conflicts==0 measured): the XOR must
// relocate whole 16-short blocks (word bits 3,4), not permute within one
// (R13's (4i+q)&7<<3 put key bits inside the burst span -> 1.57M conflicts).
// Reader key w<<4 (row>>2 = 4k+w, wave-uniform). fp32 path key (lr>>2)&7:
// worst 2-way (free, m136), reader (4k+w)&7 matches.
//
// EPI: 2 bf16 *scale | 3 bf16 | 4 fp32 +bias[row]+aux (residual)
//      5 fused qkv: local 0..63 -> qkT[n][o]=hhatT.Wqk+b (bx=li&7,by=li>>3)
//                   local 64..95 -> v[c][n]=Wv.hhatT+b   (bx=li&3,by=li>>2)
// ---------------------------------------------------------------------------
template<int EPI>
__global__ __launch_bounds__(256) void gemm128(
    const unsigned short* __restrict__ A, long sA, int lda,
    const unsigned short* __restrict__ B, long sB, int ldb,
    void* __restrict__ Dv, long sD, int ldd,
    const float* __restrict__ bias,
    const float* __restrict__ aux, long sAux,
    int K, float scale, int gx, int gy, int nbz)
{
    int bz, local;
    xcd_decode(blockIdx.x, gx * gy, nbz, bz, local);

    int bx, by;
    bool p2 = false;
    if constexpr (EPI == 5) {
        p2 = local >= 64;
        int li = p2 ? local - 64 : local;
        bx = p2 ? (li & 3) : (li & 7);
        by = p2 ? (li >> 2) : (li >> 3);
    } else {
        bx = local % gx;
        by = local / gx;
    }

    const unsigned short *Ab, *Bb;
    if constexpr (EPI == 5) {
        // lda == ldb == C_ at the EPI5 call site.
        if (p2) {
            Ab = B + (size_t)(1024 + bx * 128) * ldb;
            Bb = A + (size_t)bz * sA + (size_t)by * 128 * lda;
        } else {
            Ab = A + (size_t)bz * sA + (size_t)bx * 128 * lda;
            Bb = B + (size_t)by * 128 * ldb;
        }
    } else {
        Ab = A + (size_t)bz * sA + (size_t)bx * 128 * lda;
        Bb = B + (size_t)bz * sB + (size_t)by * 128 * ldb;
    }

    // 64 KB: A dbuf 2 x 2 sub-tiles x 4096 shorts = smem[0..3];
    //        B dbuf                                 = smem[4..7].
    // Sub-tile (c, s): A -> smem[c*2+s], B -> smem[4+c*2+s]; each holds
    // 128 rows x 32 k (two 64-row strips at +0 / +2048).
    // Epilogue reuses the first 32 KB as the output staging tile.
    __shared__ __align__(16) unsigned short smem[8][4096];

    int tid = threadIdx.x;
    int w = tid >> 6, lane = tid & 63;
    int lm = lane & 15, q = lane >> 4;
    int wrow = (w >> 1) * 64, wcol = (w & 1) * 64;

    f32x4 acc[4][4];
    #pragma unroll
    for (int i = 0; i < 4; ++i)
        #pragma unroll
        for (int j = 0; j < 4; ++j) acc[i][j] = (f32x4)(0.f);

    int srow = tid >> 2;                              // staging row (0..63)
    int skc  = (((tid & 3) ^ ((tid >> 3) & 3))) * 8;  // swizzled global chunk
    int fco  = (q ^ ((lm >> 1) & 3)) * 8;             // frag physical chunk

    const unsigned short* a0p = Ab + (size_t)srow        * lda + skc;
    const unsigned short* a1p = Ab + (size_t)(64 + srow) * lda + skc;
    const unsigned short* b0p = Bb + (size_t)srow        * ldb + skc;
    const unsigned short* b1p = Bb + (size_t)(64 + srow) * ldb + skc;

    // prologue: stage K-tile 0 (both 32-k sub-tiles) into buffer 0
    {
        cp16(&smem[0][tid * 8],        a0p);
        cp16(&smem[0][2048 + tid * 8], a1p);
        cp16(&smem[1][tid * 8],        a0p + 32);
        cp16(&smem[1][2048 + tid * 8], a1p + 32);
        cp16(&smem[4][tid * 8],        b0p);
        cp16(&smem[4][2048 + tid * 8], b1p);
        cp16(&smem[5][tid * 8],        b0p + 32);
        cp16(&smem[5][2048 + tid * 8], b1p + 32);
    }

    int nIter = K >> 6;           // 64-k tiles (K = 512 or 1024)
    for (int it = 0; it < nIter; ++it) {
        int cur = it & 1;
        __syncthreads();   // drains tile-it DMA (in flight since iter it-1)
        if (it + 1 < nIter) {
            int off = (it + 1) * 64;
            int nxt = cur ^ 1;
            cp16(&smem[nxt * 2][tid * 8],            a0p + off);
            cp16(&smem[nxt * 2][2048 + tid * 8],     a1p + off);
            cp16(&smem[nxt * 2 + 1][tid * 8],        a0p + off + 32);
            cp16(&smem[nxt * 2 + 1][2048 + tid * 8], a1p + off + 32);
            cp16(&smem[4 + nxt * 2][tid * 8],            b0p + off);
            cp16(&smem[4 + nxt * 2][2048 + tid * 8],     b1p + off);
            cp16(&smem[4 + nxt * 2 + 1][tid * 8],        b0p + off + 32);
            cp16(&smem[4 + nxt * 2 + 1][2048 + tid * 8], b1p + off + 32);
        }
        #pragma unroll
        for (int s = 0; s < 2; ++s) {
            const unsigned short* As = smem[cur * 2 + s];
            const unsigned short* Bs = smem[4 + cur * 2 + s];
            short8 af[4], bf[4];
            #pragma unroll
            for (int i = 0; i < 4; ++i)
                af[i] = *(const short8*)&As[(wrow + i * 16 + lm) * 32 + fco];
            #pragma unroll
            for (int j = 0; j < 4; ++j)
                bf[j] = *(const short8*)&Bs[(wcol + j * 16 + lm) * 32 + fco];
            #pragma unroll
            for (int i = 0; i < 4; ++i)
                #pragma unroll
                for (int j = 0; j < 4; ++j)
                    acc[i][j] = __builtin_amdgcn_mfma_f32_16x16x32_bf16(
                        af[i], bf[j], acc[i][j], 0, 0, 0);
        }
    }

    // ----------------------- coalesced epilogue ----------------------------
    __syncthreads();   // all waves done with staging LDS; safe to reuse

    if constexpr (EPI != 4) {
        // bf16: stage 128x128 tile (32 KB), key q<<4 shorts (proven R14).
        unsigned short* Ts = &smem[0][0];
        #pragma unroll
        for (int j = 0; j < 4; ++j) {
            int lc = wcol + j * 16 + lm;
            float cb = 0.f;
            if constexpr (EPI == 5) { if (!p2) cb = bias[by * 128 + lc]; }
            #pragma unroll
            for (int i = 0; i < 4; ++i) {
                #pragma unroll
                for (int r = 0; r < 4; ++r) {
                    int lr = wrow + i * 16 + q * 4 + r;
                    float vle = acc[i][j][r];
                    if constexpr (EPI == 2) vle *= scale;
                    else if constexpr (EPI == 5)
                        vle += p2 ? bias[1024 + bx * 128 + lr] : cb;
                    Ts[lr * 128 + (lc ^ (q << 4))] = f2bf(vle);
                }
            }
        }
        __syncthreads();
        size_t doff = 0;
        if constexpr (EPI == 5) { if (p2) doff = (size_t)(1u << 20); }
        unsigned short* Dp = (unsigned short*)Dv + doff +
            (size_t)bz * sD + (size_t)(bx * 128) * ldd + by * 128;
        #pragma unroll
        for (int k = 0; k < 8; ++k) {
            int flat = k * 2048 + tid * 8;          // shorts, 8-aligned
            int rr = flat >> 7, cc = flat & 127;
            // reader row-key = (rr>>2)&3 = (4k+w)&3 = w  (wave-uniform)
            short8 vv = *(const short8*)&Ts[flat ^ (w << 4)];
            *(short8*)&Dp[(size_t)rr * ldd + cc] = vv;
        }
    } else {
        // fp32 + residual: two 128x64 half-tiles (32 KB each pass).
        // Waves with w&1==h own half h's columns. Key (lr>>2)&7: worst
        // 2-way (free); reader (4k+w)&7 matches writer bijectively.
        float* Ts32 = (float*)&smem[0][0];          // 8192 floats
        float* Dp = (float*)Dv + (size_t)bz * sD + (size_t)(bx * 128) * ldd + by * 128;
        const float* Ap = aux + (size_t)bz * sAux + (size_t)(bx * 128) * ldd + by * 128;
        #pragma unroll
        for (int h = 0; h < 2; ++h) {
            if (h) __syncthreads();                 // half-0 copy-out done
            if ((w & 1) == h) {
                #pragma unroll
                for (int j = 0; j < 4; ++j) {
                    int lch = j * 16 + lm;          // 0..63 within half
                    #pragma unroll
                    for (int i = 0; i < 4; ++i) {
                        #pragma unroll
                        for (int r = 0; r < 4; ++r) {
                            int lr = wrow + i * 16 + q * 4 + r;
                            int wkey = (lr >> 2) & 7;
                            Ts32[lr * 64 + (lch ^ (wkey << 3))] =
                                acc[i][j][r] + bias[bx * 128 + lr];
                        }
                    }
                }
            }
            __syncthreads();
            #pragma unroll
            for (int k = 0; k < 8; ++k) {
                int flat = k * 1024 + tid * 4;      // floats, 4-aligned
                int rr = flat >> 6, cc = flat & 63;
                int key = (4 * k + w) & 7;          // = (rr>>2)&7, wave-uniform
                f32x4 vv = *(const f32x4*)&Ts32[flat ^ (key << 3)];
                size_t go = (size_t)rr * ldd + h * 64 + cc;
                f32x4 av = *(const f32x4*)&Ap[go];
                *(f32x4*)&Dp[go] = vv + av;
            }
        }
    }
}

// ---------------------------------------------------------------------------
// Softmax: in-place on bf16 scores. One WAVE per row (16 elems/lane),
// shuffle reductions, no barriers. Block = 4 waves = 4 rows.
// 1-D grid, XCD-pinned: keeps sc on the same XCD L2 as GEMM2/GEMM3.
// ---------------------------------------------------------------------------
__global__ __launch_bounds__(256) void softmax_kernel(
    unsigned short* __restrict__ sc, long sSc, int nbz)
{
    int bz, local;
    xcd_decode(blockIdx.x, 256, nbz, bz, local);
    int row = local * 4 + (threadIdx.x >> 6);
    int lane = threadIdx.x & 63;
    unsigned short* p = sc + (size_t)bz * sSc + (size_t)row * N_ + lane * 16;

    short8 s0 = *(const short8*)p;
    short8 s1 = *(const short8*)(p + 8);
    float v[16];
    #pragma unroll
    for (int i = 0; i < 8; ++i) {
        v[i]     = bf2f((unsigned short)s0[i]);
        v[8 + i] = bf2f((unsigned short)s1[i]);
    }
    float m = v[0];
    #pragma unroll
    for (int i = 1; i < 16; ++i) m = fmaxf(m, v[i]);
    #pragma unroll
    for (int off = 32; off > 0; off >>= 1) m = fmaxf(m, __shfl_xor(m, off, 64));

    float sum = 0.f;
    #pragma unroll
    for (int i = 0; i < 16; ++i) { v[i] = __expf(v[i] - m); sum += v[i]; }
    #pragma unroll
    for (int off = 32; off > 0; off >>= 1) sum += __shfl_xor(sum, off, 64);
    float inv = 1.f / sum;

    short8 o0, o1;
    #pragma unroll
    for (int i = 0; i < 8; ++i) {
        o0[i] = (short)f2bf(v[i] * inv);
        o1[i] = (short)f2bf(v[8 + i] * inv);
    }
    *(short8*)p = o0;
    *(short8*)(p + 8) = o1;
}

// ---------------------------------------------------------------------------
extern "C" void kernel_launch(void* const* d_in, const int* in_sizes, int n_in,
                              void* d_out, int out_size, void* d_ws, size_t ws_size,
                              hipStream_t stream) {
    const float* x      = (const float*)d_in[0];
    const float* norm_w = (const float*)d_in[1];
    const float* norm_b = (const float*)d_in[2];
    const float* qkv_w  = (const float*)d_in[3];
    const float* qkv_b  = (const float*)d_in[4];
    const float* proj_w = (const float*)d_in[5];
    const float* proj_b = (const float*)d_in[6];
    float* out = (float*)d_out;

    // Fixed region: stats (8 KB) + bf16 weights (2 MB).
    char* ws = (char*)d_ws;
    float* stats = (float*)ws;
    unsigned short* wqkv  = (unsigned short*)(ws + 8192);   // 1536x512
    unsigned short* wproj = wqkv + (size_t)OC3_ * C_;       // 512x512
    char* base = (char*)(wproj + (size_t)C_ * C_);
    const size_t fixed = 8192 + (size_t)OC3_ * C_ * 2 + (size_t)C_ * C_ * 2;

    // Per-batch aliased region: 6 MB.
    //   [0,2M)  qkT bf16 [n][1024]
    //   [2,3M)  v bf16 [c][n]     (= qkT + (1<<20) shorts; EPI5 part 2)
    //   [3,4M)  hhatT bf16 [n][c] -> after GEMM2 reused as houtT bf16 [n][c]
    //   [4,6M)  sc bf16 [n][m]    -> softmax in-place -> attn
    const size_t REG = 6u << 20;
    const long RSH = (long)(REG / 2);         // region stride in shorts

    size_t avail = ws_size > fixed ? ws_size - fixed : 0;
    int chunk = (int)(avail / REG);
    if (chunk < 1) chunk = 1;
    if (chunk > B_) chunk = B_;

    prep_kernel<<<dim3(2048), dim3(256), 0, stream>>>(
        x, stats, qkv_w, wqkv, proj_w, wproj);

    const float scale = 0.044194173824159216f;  // 512^-0.5

    unsigned short* qkT   = (unsigned short*)base;
    unsigned short* vbuf  = (unsigned short*)(base + (2u << 20));
    unsigned short* hhatT = (unsigned short*)(base + (3u << 20));
    unsigned short* houtT = (unsigned short*)(base + (3u << 20)); // aliases hhatT
    unsigned short* sc    = (unsigned short*)(base + (4u << 20)); // scores/attn

    for (int b0 = 0; b0 < B_; b0 += chunk) {
        int nb = B_ - b0 < chunk ? B_ - b0 : chunk;

        hhatT_kernel<<<dim3(128 * nb), dim3(256), 0, stream>>>(
            x, stats, norm_w, norm_b, hhatT, RSH, b0, nb);

        // GEMM1 fused (EPI5): qkT[n][0:1024] (+bias[col]) AND v[c][n]
        // (+bias[1024+row]); 96 blocks/batch (64 qk + 32 v).
        gemm128<5><<<dim3(96 * nb), dim3(256), 0, stream>>>(
            hhatT, RSH, C_,  wqkv, 0, C_,
            qkT, RSH, 1024,  qkv_b, nullptr, 0, C_, 0.f, 96, 1, nb);

        // GEMM2: sc[n][m] = bf16( scale * qkT[n][0:512] . qkT[m][512:1024] )
        gemm128<2><<<dim3(8 * 8 * nb), dim3(256), 0, stream>>>(
            qkT, RSH, 1024,  qkT + 512, RSH, 1024,
            sc, RSH, N_,  nullptr, nullptr, 0, C_, scale, 8, 8, nb);

        softmax_kernel<<<dim3(256 * nb), dim3(256), 0, stream>>>(sc, RSH, nb);

        // GEMM3: houtT[n][c] = attn[n][:] . v[c][:]   (K = 1024)
        gemm128<3><<<dim3(8 * 4 * nb), dim3(256), 0, stream>>>(
            sc, RSH, N_,  vbuf, RSH, N_,
            houtT, RSH, C_,  nullptr, nullptr, 0, N_, 0.f, 8, 4, nb);

        // GEMM4: out[o][n] = pw[o][:] . houtT[n][:] + pb[o] + x[o][n]
        gemm128<4><<<dim3(4 * 8 * nb), dim3(256), 0, stream>>>(
            wproj, 0, C_,  houtT, RSH, C_,
            out + (size_t)b0 * C_ * N_, (long)C_ * N_, N_,
            proj_b, x + (size_t)b0 * C_ * N_, (long)C_ * N_, C_, 0.f, 4, 8, nb);
    }
}